// Round 15
// baseline (284.623 us; speedup 1.0000x reference)
//
#include <hip/hip_runtime.h>
#include <hip/hip_bf16.h>

constexpr int kN = 10000;
constexpr int kE = 25000;
constexpr int kB = 128;
constexpr int kNF = 32;
constexpr int kEF = 8;
constexpr int kD = 64;
constexpr int kGrp = 196;          // 128-edge groups (25088 padded)
constexpr int kEPad = kGrp * 128;  // 25088
constexpr int kNCap = 320;         // s2s LDS node cap (global fallback beyond)

typedef __attribute__((ext_vector_type(8))) short short8;
typedef __attribute__((ext_vector_type(4))) float floatx4;
typedef __attribute__((ext_vector_type(16))) float floatx16;
typedef _Float16 half8 __attribute__((ext_vector_type(8)));

union HU { uint4 u; half8 h; short8 s; };

__device__ __forceinline__ unsigned short f2h(float f) {
  union { _Float16 h; unsigned short u; } cv;
  cv.h = (_Float16)f;
  return cv.u;
}
__device__ __forceinline__ unsigned pkrtz(float lo, float hi) {
  unsigned r;
  asm("v_cvt_pkrtz_f16_f32 %0, %1, %2" : "=v"(r) : "v"(lo), "v"(hi));
  return r;
}
__device__ __forceinline__ float sigmf(float x) { return 1.f / (1.f + __expf(-x)); }
__device__ __forceinline__ float tanh_(float x) { return 1.f - 2.f / (__expf(2.f * x) + 1.f); }

// ============ fused setup: dense0 | hidden fp16 [grp][h128][e128] | prep_b | deg | bounds ====
constexpr int kBlkDense = 2500;                 // kN*64/256
constexpr int kBlkHid   = 12544;                // 196*128*128/256
constexpr int kBlkPrep  = 258;                  // 1032 slots * 64 lanes / 256
constexpr int kBlkDeg   = 98;
constexpr int kB0H = kBlkDense;                 // 2500
constexpr int kB0P = kB0H + kBlkHid;            // 15044
constexpr int kB0G = kB0P + kBlkPrep;           // 15302
constexpr int kB0B = kB0G + kBlkDeg;            // 15400
constexpr int kBlkSetup = kB0B + 1;             // 15401

__global__ __launch_bounds__(256) void k_setup(
    const float* __restrict__ x, const float* __restrict__ W0, const float* __restrict__ b0,
    const float* __restrict__ ea, const float* __restrict__ We1, const float* __restrict__ be1,
    const float* __restrict__ We2, const float* __restrict__ be2,
    const int* __restrict__ ei, const int* __restrict__ batch,
    float* __restrict__ outn, unsigned short* __restrict__ hid7,
    unsigned short* __restrict__ Bc2, float* __restrict__ deg, int* __restrict__ start) {
  const int blk = blockIdx.x, t = threadIdx.x;
  if (blk < kB0H) {                   // ---- dense0: out = relu(x@W0+b0), [N,64]
    int gid = blk * 256 + t;
    int n = gid >> 6, f = gid & 63;
    float acc = b0[f];
    const float* xr = x + n * kNF;
#pragma unroll
    for (int j = 0; j < kNF; ++j) acc += xr[j] * W0[j * kD + f];
    outn[gid] = fmaxf(acc, 0.f);
  } else if (blk < kB0P) {            // ---- hidden: hid7[grp][h 128][e 128], fp16
    int gid = (blk - kB0H) * 256 + t;
    int e_loc = gid & 127, h = (gid >> 7) & 127, grp = gid >> 14;
    int e = grp * 128 + e_loc;
    float r = 0.f;
    if (e < kE) {
      float acc = be1[h];
      const float* er = ea + e * kEF;
#pragma unroll
      for (int j = 0; j < kEF; ++j) acc += er[j] * We1[j * 128 + h];
      r = fmaxf(acc, 0.f);
    }
    hid7[gid] = f2h(r);
  } else if (blk < kB0G) {            // ---- prep B: fragment-major Bc2 (32x32x16), fp16
    int lg = (blk - kB0P) * 256 + t;
    int lane = lg & 63, slot = lg >> 6;            // slot 0..1031
    int fcol, dbase;
    const float* srcmat;
    if (slot < 1024) {
      int nf_ = slot & 1, hdb = slot >> 1;         // slot = (h*4+db)*2+nf
      int db = hdb & 3, h = hdb >> 2;
      fcol = nf_ * 32 + (lane & 31);
      dbase = db * 16 + (lane >> 5) * 8;
      srcmat = We2 + (size_t)h * 4096;
    } else {
      int s = slot - 1024;
      int db = s >> 1, nf_ = s & 1;
      fcol = nf_ * 32 + (lane & 31);
      dbase = db * 16 + (lane >> 5) * 8;
      srcmat = be2;
    }
    unsigned short v[8];
#pragma unroll
    for (int j = 0; j < 8; ++j) v[j] = f2h(srcmat[(size_t)(dbase + j) * 64 + fcol]);
    *(short8*)(Bc2 + (size_t)slot * 512 + lane * 8) = *(short8*)v;
  } else if (blk < kB0B) {            // ---- degree
    int e = (blk - kB0G) * 256 + t;
    if (e < kE) atomicAdd(&deg[ei[kE + e]], 1.f);
  } else {                            // ---- per-graph bounds (batch sorted)
    if (t > kB) return;
    int lo = 0, hi = kN;
    while (lo < hi) { int mid = (lo + hi) >> 1; if (batch[mid] < t) lo = mid + 1; else hi = mid; }
    start[t] = lo;
  }
}

// ============ CSR build: scan (1 block) + scatter (saves perm[e]) ============
__global__ __launch_bounds__(256) void k_csr(const float* __restrict__ deg,
                                             int* __restrict__ ptr) {
  __shared__ int ps[256];
  int t = threadIdx.x;
  int base = t * 40;                       // 256*40 = 10240 >= kN
  int s = 0;
#pragma unroll 8
  for (int j = 0; j < 40; ++j) {
    int n = base + j;
    if (n < kN) s += (int)deg[n];
  }
  ps[t] = s;
  __syncthreads();
  for (int off = 1; off < 256; off <<= 1) {
    int v = (t >= off) ? ps[t - off] : 0;
    __syncthreads();
    ps[t] += v;
    __syncthreads();
  }
  int run = ps[t] - s;                     // exclusive prefix of this chunk
  for (int j = 0; j < 40; ++j) {
    int n = base + j;
    if (n < kN) { ptr[n] = run; run += (int)deg[n]; }
  }
  if (t == 255) ptr[kN] = ps[255];
}

__global__ __launch_bounds__(256) void k_scatter(const int* __restrict__ ei,
    const int* __restrict__ ptr, int* __restrict__ cnt, int* __restrict__ perm) {
  int e = blockIdx.x * 256 + threadIdx.x;
  if (e < kE) {
    int d = ei[kE + e];
    int pos = atomicAdd(&cnt[d], 1);
    perm[e] = ptr[d] + pos;                // edge e's row in csr-ordered msg buffer
  }
}

// ============ message GEMM v10: 128 edges x 32-h K-quarter; waves M-split ============
// Grid (196, 4). All 4 waves read the SAME B slots (L1-shared); B per block 256 KB
// (half of v9 per edge). No intra-block K-split -> no reduce, no res LDS, no barriers
// after staging. Each wave: M=32 (1 mf), N=64 (2 nf); direct scattered stores via perm.
__global__ __launch_bounds__(256) void k_msgA(const int* __restrict__ ei,
    const float* __restrict__ outn, const unsigned short* __restrict__ hid7,
    const unsigned short* __restrict__ Bc2, const int* __restrict__ perm,
    float* __restrict__ msg, size_t msgStride) {
  __shared__ __align__(16) unsigned short hidS[32 * 128];   // [h_loc][e_loc] fp16, 8 KB
  const int t = threadIdx.x, lane = t & 63, wave = t >> 6;
  const int er = lane & 31, hi5 = lane >> 5;
  const int grp = blockIdx.x, qy = blockIdx.y, e0 = grp * 128;
  float* __restrict__ msgP = msg + (size_t)qy * msgStride;
  {   // stage hid K-quarter tile (8 KB linear): hid7 + grp*16384 + qy*4096
    const char* hsrc = (const char*)(hid7 + (size_t)grp * 16384 + qy * 4096);
#pragma unroll
    for (int i = 0; i < 2; ++i) {
      int off = (wave * 2 + i) * 1024 + lane * 16;
      __builtin_amdgcn_global_load_lds(
          (const __attribute__((address_space(1))) void*)(hsrc + off),
          (__attribute__((address_space(3))) void*)((char*)hidS + off), 16, 0, 0);
    }
  }
  // B prefetch: one h (8 slots: 4 db x 2 nf) in flight; same slots for all waves
  const unsigned short* bp = Bc2 + (size_t)(qy * 32 * 8) * 512 + lane * 8;
  short8 bvr[8];
#pragma unroll
  for (int j = 0; j < 8; ++j) bvr[j] = *(const short8*)(bp + (size_t)j * 512);
  // gather out[src] rows -> packed fp16: 1 mf (32 edges/wave) x 4 db x 4 dwords
  HU o8[4];
  {
    int e = e0 + wave * 32 + er;
    int s = (e < kE) ? ei[e] : 0;
    const float* base = outn + (size_t)s * 64 + hi5 * 8;
#pragma unroll
    for (int db = 0; db < 4; ++db) {
      floatx4 q0 = *(const floatx4*)(base + db * 16);
      floatx4 q1 = *(const floatx4*)(base + db * 16 + 4);
      o8[db].u = (uint4){pkrtz(q0.x, q0.y), pkrtz(q0.z, q0.w),
                         pkrtz(q1.x, q1.y), pkrtz(q1.z, q1.w)};
    }
  }
  __syncthreads();   // hidS ready

  floatx16 acc[2];
#pragma unroll
  for (int i = 0; i < 16; ++i) { acc[0][i] = 0.f; acc[1][i] = 0.f; }

#pragma unroll 2
  for (int hh = 0; hh < 32; ++hh) {
    unsigned p0 = (unsigned)hidS[hh * 128 + wave * 32 + er] * 0x10001u;  // fp16 splat
    HU hv;
    hv.u = (uint4){p0, p0, p0, p0};
    const unsigned short* bpn = bp + (size_t)((hh + 1) * 8) * 512;   // next h (max abs slot 1031)
#pragma unroll
    for (int db = 0; db < 4; ++db) {
      HU bv0, bv1;
      bv0.s = bvr[db * 2]; bv1.s = bvr[db * 2 + 1];
      bvr[db * 2]     = *(const short8*)(bpn + (size_t)(db * 2) * 512);
      bvr[db * 2 + 1] = *(const short8*)(bpn + (size_t)(db * 2 + 1) * 512);
      half8 a = o8[db].h * hv.h;             // 4 v_pk_mul_f16, no converts
      acc[0] = __builtin_amdgcn_mfma_f32_32x32x16_f16(a, bv0.h, acc[0], 0, 0, 0);
      acc[1] = __builtin_amdgcn_mfma_f32_32x32x16_f16(a, bv1.h, acc[1], 0, 0, 0);
    }
  }
  if (qy == 3) {   // bias: msg += out @ reshape(be2,64,64) (A = out, fp16), all waves
#pragma unroll
    for (int db = 0; db < 4; ++db) {
      HU bv0, bv1;
      bv0.s = *(const short8*)(Bc2 + (size_t)(1024 + db * 2) * 512 + lane * 8);
      bv1.s = *(const short8*)(Bc2 + (size_t)(1024 + db * 2 + 1) * 512 + lane * 8);
      acc[0] = __builtin_amdgcn_mfma_f32_32x32x16_f16(o8[db].h, bv0.h, acc[0], 0, 0, 0);
      acc[1] = __builtin_amdgcn_mfma_f32_32x32x16_f16(o8[db].h, bv1.h, acc[1], 0, 0, 0);
    }
  }
  // direct scattered stores (CSR row via perm); D layout: col=lane&31,
  // row=(reg&3)+8*(reg>>2)+4*hi5. Lanes 0-31 of a reg = 128B contiguous run.
#pragma unroll
  for (int rg = 0; rg < 16; ++rg) {
    int row = (rg & 3) + 8 * (rg >> 2) + 4 * hi5;
    int e = e0 + wave * 32 + row;
    if (e < kE) {
      float* rp = msgP + (size_t)perm[e] * 64 + er;
      rp[0]  = acc[0][rg];
      rp[32] = acc[1][rg];
    }
  }
}

// ==== NNConv-combine + GRU: contiguous CSR gather of 4 K-quarter partials ====
__global__ __launch_bounds__(256) void k_update(const float* __restrict__ msg,
    size_t msgStride, const int* __restrict__ ptr, const float* __restrict__ deg,
    const float* __restrict__ root, const float* __restrict__ convb,
    const float* __restrict__ Wi, const float* __restrict__ bi,
    const float* __restrict__ Wh, const float* __restrict__ bh,
    float* __restrict__ out) {
  __shared__ float sh_out[8][64];
  __shared__ float sh_m[8][64];
  int t = threadIdx.x, lane = t & 63, w = t >> 6;
  int nb = blockIdx.x * 8;
#pragma unroll
  for (int i = 0; i < 2; ++i) {
    int idx = t + i * 256;
    sh_out[idx >> 6][idx & 63] = out[(size_t)(nb + (idx >> 6)) * 64 + (idx & 63)];
  }
  __syncthreads();
  int n0 = w * 2;
  float acc[2];
#pragma unroll
  for (int i = 0; i < 2; ++i) {
    int n = nb + n0 + i;
    float dg = fmaxf(deg[n], 1.f);
    float s = 0.f;
    int p0 = ptr[n], p1 = ptr[n + 1];
    for (int k = p0; k < p1; ++k) {          // contiguous rows x 4 partial buffers
      size_t o2 = (size_t)k * 64 + lane;
      s += msg[o2] + msg[o2 + msgStride] + msg[o2 + 2 * msgStride] + msg[o2 + 3 * msgStride];
    }
    acc[i] = s / dg + convb[lane];
  }
  for (int d = 0; d < 64; ++d) {
    float rv = root[d * 64 + lane];
#pragma unroll
    for (int i = 0; i < 2; ++i) acc[i] += sh_out[n0 + i][d] * rv;
  }
#pragma unroll
  for (int i = 0; i < 2; ++i) sh_m[n0 + i][lane] = fmaxf(acc[i], 0.f);
  __syncthreads();
  float ir[2] = {}, iz[2] = {}, ig[2] = {}, hr[2] = {}, hz[2] = {}, hg[2] = {};
  for (int d = 0; d < 64; ++d) {
    float wi0 = Wi[d * 192 + lane], wi1 = Wi[d * 192 + 64 + lane], wi2 = Wi[d * 192 + 128 + lane];
    float wh0 = Wh[d * 192 + lane], wh1 = Wh[d * 192 + 64 + lane], wh2 = Wh[d * 192 + 128 + lane];
#pragma unroll
    for (int i = 0; i < 2; ++i) {
      float mv = sh_m[n0 + i][d], hv = sh_out[n0 + i][d];
      ir[i] += mv * wi0; iz[i] += mv * wi1; ig[i] += mv * wi2;
      hr[i] += hv * wh0; hz[i] += hv * wh1; hg[i] += hv * wh2;
    }
  }
  float bi0 = bi[lane], bi1 = bi[64 + lane], bi2 = bi[128 + lane];
  float bh0 = bh[lane], bh1 = bh[64 + lane], bh2 = bh[128 + lane];
#pragma unroll
  for (int i = 0; i < 2; ++i) {
    float r = sigmf(ir[i] + bi0 + hr[i] + bh0);
    float z = sigmf(iz[i] + bi1 + hz[i] + bh1);
    float nn = tanh_(ig[i] + bi2 + r * (hg[i] + bh2));
    float h = sh_out[n0 + i][lane];
    out[(size_t)(nb + n0 + i) * 64 + lane] = (1.f - z) * nn + z * h;
  }
}

// ============ all 3 Set2Set steps + head1; graph's node rows staged in LDS ============
__global__ __launch_bounds__(256) void k_s2s3(const float* __restrict__ out,
    const int* __restrict__ start, const float* __restrict__ Wli,
    const float* __restrict__ bli, const float* __restrict__ Wlh,
    const float* __restrict__ blh, const float* __restrict__ Wr1,
    const float* __restrict__ br1, float* __restrict__ y1) {
  __shared__ float sno[kNCap * 65];     // node rows, stride 65 (bank-conflict-free)
  __shared__ float ebuf[1024];
  __shared__ float qs[128], hls[64], cls[64], gates[256];
  __shared__ float part[4][64];
  __shared__ float sred[8];
  int b = blockIdx.x, t = threadIdx.x, lane = t & 63, w = t >> 6;
  int s0 = start[b], s1 = start[b + 1];
  int cnt = s1 - s0; if (cnt > 1024) cnt = 1024;
  int cstg = cnt < kNCap ? cnt : kNCap;
  for (int i = t; i < cstg * 64; i += 256)
    sno[(i >> 6) * 65 + (i & 63)] = out[(size_t)(s0 + (i >> 6)) * 64 + (i & 63)];
  if (t < 128) qs[t] = 0.f;
  if (t < 64) { hls[t] = 0.f; cls[t] = 0.f; }
  __syncthreads();
  for (int it = 0; it < 3; ++it) {
    float g = bli[t] + blh[t];
    for (int j = 0; j < 128; ++j) g += qs[j] * Wli[j * 256 + t];
    for (int j = 0; j < 64; ++j) g += hls[j] * Wlh[j * 256 + t];
    gates[t] = g;
    __syncthreads();
    if (t < 64) {                      // gate order i, f, g, o
      float ig = sigmf(gates[t]), fg = sigmf(gates[64 + t]);
      float gg = tanh_(gates[128 + t]), og = sigmf(gates[192 + t]);
      float c = fg * cls[t] + ig * gg;
      float h = og * tanh_(c);
      cls[t] = c; hls[t] = h;
      qs[t] = h;                       // q part of q_star
    }
    __syncthreads();
    for (int n = t; n < cnt; n += 256) {        // e[n] = <out[n], q>
      float e = 0.f;
      if (n < kNCap) {
        const float* row = &sno[n * 65];
#pragma unroll 16
        for (int d = 0; d < 64; ++d) e += row[d] * hls[d];
      } else {
        const float* row = out + (size_t)(s0 + n) * 64;
        for (int d = 0; d < 64; ++d) e += row[d] * hls[d];
      }
      ebuf[n] = e;
    }
    __syncthreads();
    float mx = -3.4e38f;
    for (int idx = t; idx < cnt; idx += 256) mx = fmaxf(mx, ebuf[idx]);
#pragma unroll
    for (int m = 1; m < 64; m <<= 1) mx = fmaxf(mx, __shfl_xor(mx, m, 64));
    if (lane == 0) sred[w] = mx;
    __syncthreads();
    mx = fmaxf(fmaxf(sred[0], sred[1]), fmaxf(sred[2], sred[3]));
    float s = 0.f;
    for (int idx = t; idx < cnt; idx += 256) {
      float a = __expf(ebuf[idx] - mx);
      ebuf[idx] = a; s += a;
    }
#pragma unroll
    for (int m = 1; m < 64; m <<= 1) s += __shfl_xor(s, m, 64);
    if (lane == 0) sred[4 + w] = s;
    __syncthreads();
    s = sred[4] + sred[5] + sred[6] + sred[7];
    float rs = 1.f / fmaxf(s, 1e-12f);
    float pr = 0.f;
    for (int n = w; n < cnt; n += 4) {
      float a = ebuf[n];
      pr += a * ((n < kNCap) ? sno[n * 65 + lane] : out[(size_t)(s0 + n) * 64 + lane]);
    }
    part[w][lane] = pr;
    __syncthreads();
    if (t < 64)
      qs[64 + t] = (part[0][t] + part[1][t] + part[2][t] + part[3][t]) * rs;
    __syncthreads();
  }
  if (t < 64) {                        // head1: y1 = q_star @ Wr1 + br1
    float acc = br1[t];
    for (int j = 0; j < 128; ++j) acc += qs[j] * Wr1[j * 64 + t];
    y1[b * 64 + t] = acc;
  }
}

// ============ head2: BatchNorm (batch stats) + relu + Wr2 ============
__global__ __launch_bounds__(256) void k_head2(const float* __restrict__ y1,
    const float* __restrict__ gamma, const float* __restrict__ beta,
    const float* __restrict__ Wr2, const float* __restrict__ br2,
    float* __restrict__ outp) {
  __shared__ float mu[64], ri[64];
  int t = threadIdx.x;
  if (t < 64) {
    float s1 = 0.f, s2 = 0.f;
    for (int b = 0; b < kB; ++b) { float v = y1[b * 64 + t]; s1 += v; s2 += v * v; }
    float m = s1 / (float)kB;
    mu[t] = m; ri[t] = rsqrtf(s2 / (float)kB - m * m + 1e-5f);
  }
  __syncthreads();
  if (t < kB) {
    float acc = br2[0];
    for (int f = 0; f < 64; ++f) {
      float v = (y1[t * 64 + f] - mu[f]) * ri[f] * gamma[f] + beta[f];
      acc += fmaxf(v, 0.f) * Wr2[f];
    }
    outp[t] = acc;
  }
}

extern "C" void kernel_launch(void* const* d_in, const int* in_sizes, int n_in,
                              void* d_out, int out_size, void* d_ws, size_t ws_size,
                              hipStream_t stream) {
  const float* x     = (const float*)d_in[0];
  const int*   ei    = (const int*)d_in[1];
  const float* ea    = (const float*)d_in[2];
  const int*   batch = (const int*)d_in[3];
  const float* W0    = (const float*)d_in[4];
  const float* b0    = (const float*)d_in[5];
  const float* We1   = (const float*)d_in[6];
  const float* be1   = (const float*)d_in[7];
  const float* We2   = (const float*)d_in[8];
  const float* be2   = (const float*)d_in[9];
  const float* root  = (const float*)d_in[10];
  const float* convb = (const float*)d_in[11];
  const float* Wi    = (const float*)d_in[12];
  const float* bi    = (const float*)d_in[13];
  const float* Wh    = (const float*)d_in[14];
  const float* bh    = (const float*)d_in[15];
  const float* Wli   = (const float*)d_in[16];
  const float* bli   = (const float*)d_in[17];
  const float* Wlh   = (const float*)d_in[18];
  const float* blh   = (const float*)d_in[19];
  const float* Wr1   = (const float*)d_in[20];
  const float* br1   = (const float*)d_in[21];
  const float* gamma = (const float*)d_in[22];
  const float* beta  = (const float*)d_in[23];
  const float* Wr2   = (const float*)d_in[24];
  const float* br2   = (const float*)d_in[25];
  (void)in_sizes; (void)n_in; (void)out_size; (void)ws_size;

  char* ws = (char*)d_ws;
  size_t off = 0;
  auto take = [&](size_t bytes) {
    char* p = ws + off;
    off += (bytes + 255) & ~(size_t)255;
    return p;
  };
  // zero-region: deg + cnt (contiguous, one memset)
  float* deg  = (float*)take((size_t)kN * 4);
  int*   cnt  = (int*)take((size_t)kN * 4);
  size_t zeroBytes = off;
  int*   ptr   = (int*)take((size_t)(kN + 1) * 4);
  int*   perm  = (int*)take((size_t)kE * 4);
  int*   start = (int*)take(256 * 4);
  float* outn  = (float*)take((size_t)kN * kD * 4);
  const size_t msgStride = (size_t)kEPad * kD;                         // elems per partial
  float* msg  = (float*)take(4 * msgStride * 4);                       // 25.6 MB (4 partials)
  unsigned short* hid7 = (unsigned short*)take((size_t)kGrp * 16384 * 2);  // 6.4 MB
  unsigned short* Bc2  = (unsigned short*)take((size_t)1032 * 512 * 2);    // 1.03 MB
  float* y1    = (float*)take((size_t)kB * 64 * 4);

  hipMemsetAsync(deg, 0, zeroBytes, stream);
  k_setup<<<kBlkSetup, 256, 0, stream>>>(x, W0, b0, ea, We1, be1, We2, be2, ei, batch,
                                         outn, hid7, Bc2, deg, start);
  k_csr<<<1, 256, 0, stream>>>(deg, ptr);
  k_scatter<<<(kE + 255) / 256, 256, 0, stream>>>(ei, ptr, cnt, perm);
  dim3 gm(kGrp, 4);
  for (int s = 0; s < 3; ++s) {
    k_msgA<<<gm, 256, 0, stream>>>(ei, outn, hid7, Bc2, perm, msg, msgStride);
    k_update<<<kN / 8, 256, 0, stream>>>(msg, msgStride, ptr, deg, root, convb,
                                         Wi, bi, Wh, bh, outn);
  }
  k_s2s3<<<kB, 256, 0, stream>>>(outn, start, Wli, bli, Wlh, blh, Wr1, br1, y1);
  k_head2<<<1, 256, 0, stream>>>(y1, gamma, beta, Wr2, br2, (float*)d_out);
}

// Round 16
// 273.002 us; speedup vs baseline: 1.0426x; 1.0426x over previous
//
#include <hip/hip_runtime.h>
#include <hip/hip_bf16.h>

constexpr int kN = 10000;
constexpr int kE = 25000;
constexpr int kB = 128;
constexpr int kNF = 32;
constexpr int kEF = 8;
constexpr int kD = 64;
constexpr int kGrp = 392;          // 64-edge groups (25088 padded)
constexpr int kEPad = kGrp * 64;   // 25088
constexpr int kNCap = 320;         // s2s LDS node cap (global fallback beyond)

typedef __attribute__((ext_vector_type(8))) short short8;
typedef __attribute__((ext_vector_type(4))) float floatx4;
typedef __attribute__((ext_vector_type(16))) float floatx16;
typedef _Float16 half8 __attribute__((ext_vector_type(8)));

union HU { uint4 u; half8 h; short8 s; };

__device__ __forceinline__ unsigned short f2h(float f) {
  union { _Float16 h; unsigned short u; } cv;
  cv.h = (_Float16)f;
  return cv.u;
}
__device__ __forceinline__ unsigned pkrtz(float lo, float hi) {
  unsigned r;
  asm("v_cvt_pkrtz_f16_f32 %0, %1, %2" : "=v"(r) : "v"(lo), "v"(hi));
  return r;
}
__device__ __forceinline__ float sigmf(float x) { return 1.f / (1.f + __expf(-x)); }
__device__ __forceinline__ float tanh_(float x) { return 1.f - 2.f / (__expf(2.f * x) + 1.f); }

// ============ fused setup: dense0 | hidden fp16 [grp][h128][e64] | prep_b | deg | bounds ====
constexpr int kBlkDense = 2500;                 // kN*64/256
constexpr int kBlkHid   = 12544;                // 392*128*64/256
constexpr int kBlkPrep  = 258;                  // 1032 slots * 64 lanes / 256
constexpr int kBlkDeg   = 98;
constexpr int kB0H = kBlkDense;                 // 2500
constexpr int kB0P = kB0H + kBlkHid;            // 15044
constexpr int kB0G = kB0P + kBlkPrep;           // 15302
constexpr int kB0B = kB0G + kBlkDeg;            // 15400
constexpr int kBlkSetup = kB0B + 1;             // 15401

__global__ __launch_bounds__(256) void k_setup(
    const float* __restrict__ x, const float* __restrict__ W0, const float* __restrict__ b0,
    const float* __restrict__ ea, const float* __restrict__ We1, const float* __restrict__ be1,
    const float* __restrict__ We2, const float* __restrict__ be2,
    const int* __restrict__ ei, const int* __restrict__ batch,
    float* __restrict__ outn, unsigned short* __restrict__ hid7,
    unsigned short* __restrict__ Bc2, float* __restrict__ deg, int* __restrict__ start) {
  const int blk = blockIdx.x, t = threadIdx.x;
  if (blk < kB0H) {                   // ---- dense0: out = relu(x@W0+b0), [N,64]
    int gid = blk * 256 + t;
    int n = gid >> 6, f = gid & 63;
    float acc = b0[f];
    const float* xr = x + n * kNF;
#pragma unroll
    for (int j = 0; j < kNF; ++j) acc += xr[j] * W0[j * kD + f];
    outn[gid] = fmaxf(acc, 0.f);
  } else if (blk < kB0P) {            // ---- hidden: hid7[grp][h 128][e 64], fp16
    int gid = (blk - kB0H) * 256 + t;
    int e_loc = gid & 63, h = (gid >> 6) & 127, grp = gid >> 13;
    int e = grp * 64 + e_loc;
    float r = 0.f;
    if (e < kE) {
      float acc = be1[h];
      const float* er = ea + e * kEF;
#pragma unroll
      for (int j = 0; j < kEF; ++j) acc += er[j] * We1[j * 128 + h];
      r = fmaxf(acc, 0.f);
    }
    hid7[gid] = f2h(r);
  } else if (blk < kB0G) {            // ---- prep B: fragment-major Bc2 (32x32x16), fp16
    int lg = (blk - kB0P) * 256 + t;
    int lane = lg & 63, slot = lg >> 6;            // slot 0..1031
    int fcol, dbase;
    const float* srcmat;
    if (slot < 1024) {
      int nf_ = slot & 1, hdb = slot >> 1;         // slot = (h*4+db)*2+nf
      int db = hdb & 3, h = hdb >> 2;
      fcol = nf_ * 32 + (lane & 31);
      dbase = db * 16 + (lane >> 5) * 8;
      srcmat = We2 + (size_t)h * 4096;
    } else {
      int s = slot - 1024;
      int db = s >> 1, nf_ = s & 1;
      fcol = nf_ * 32 + (lane & 31);
      dbase = db * 16 + (lane >> 5) * 8;
      srcmat = be2;
    }
    unsigned short v[8];
#pragma unroll
    for (int j = 0; j < 8; ++j) v[j] = f2h(srcmat[(size_t)(dbase + j) * 64 + fcol]);
    *(short8*)(Bc2 + (size_t)slot * 512 + lane * 8) = *(short8*)v;
  } else if (blk < kB0B) {            // ---- degree
    int e = (blk - kB0G) * 256 + t;
    if (e < kE) atomicAdd(&deg[ei[kE + e]], 1.f);
  } else {                            // ---- per-graph bounds (batch sorted)
    if (t > kB) return;
    int lo = 0, hi = kN;
    while (lo < hi) { int mid = (lo + hi) >> 1; if (batch[mid] < t) lo = mid + 1; else hi = mid; }
    start[t] = lo;
  }
}

// ============ CSR build: scan (1 block) + scatter (saves perm[e]) ============
__global__ __launch_bounds__(256) void k_csr(const float* __restrict__ deg,
                                             int* __restrict__ ptr) {
  __shared__ int ps[256];
  int t = threadIdx.x;
  int base = t * 40;                       // 256*40 = 10240 >= kN
  int s = 0;
#pragma unroll 8
  for (int j = 0; j < 40; ++j) {
    int n = base + j;
    if (n < kN) s += (int)deg[n];
  }
  ps[t] = s;
  __syncthreads();
  for (int off = 1; off < 256; off <<= 1) {
    int v = (t >= off) ? ps[t - off] : 0;
    __syncthreads();
    ps[t] += v;
    __syncthreads();
  }
  int run = ps[t] - s;                     // exclusive prefix of this chunk
  for (int j = 0; j < 40; ++j) {
    int n = base + j;
    if (n < kN) { ptr[n] = run; run += (int)deg[n]; }
  }
  if (t == 255) ptr[kN] = ps[255];
}

__global__ __launch_bounds__(256) void k_scatter(const int* __restrict__ ei,
    const int* __restrict__ ptr, int* __restrict__ cnt, int* __restrict__ perm) {
  int e = blockIdx.x * 256 + threadIdx.x;
  if (e < kE) {
    int d = ei[kE + e];
    int pos = atomicAdd(&cnt[d], 1);
    perm[e] = ptr[d] + pos;                // edge e's row in csr-ordered msg buffer
  }
}

// ============ message GEMM v11: 512-thread block, 8-wave K-split, full K=128 ============
// Grid 392. Block = 64 edges x full K. Wave w handles h in [w*16, w*16+16).
// A-gather done ONCE per block (was 2x in the (392,2) layout); single msg buffer
// (k_update read traffic halves). Chunked 8-way K-reduce in LDS; conflict-free.
__global__ __launch_bounds__(512) void k_msgB(const int* __restrict__ ei,
    const float* __restrict__ outn, const unsigned short* __restrict__ hid7,
    const unsigned short* __restrict__ Bc2, const int* __restrict__ perm,
    float* __restrict__ msg) {
  __shared__ __align__(16) unsigned short hidS[128 * 64];   // [h][e_loc] fp16, 16 KB
  __shared__ __align__(16) float res[8][32 * 64];           // per-wave mf-chunk, 64 KB
  const int t = threadIdx.x, lane = t & 63, wave = t >> 6;  // wave 0..7
  const int er = lane & 31, hi5 = lane >> 5;
  const int grp = blockIdx.x, e0 = grp * 64;
  {   // stage full hid tile (16 KB linear), 2 instrs/wave
    const char* hsrc = (const char*)(hid7 + (size_t)grp * 8192);
#pragma unroll
    for (int i = 0; i < 2; ++i) {
      int off = (wave * 2 + i) * 1024 + lane * 16;
      __builtin_amdgcn_global_load_lds(
          (const __attribute__((address_space(1))) void*)(hsrc + off),
          (__attribute__((address_space(3))) void*)((char*)hidS + off), 16, 0, 0);
    }
  }
  // B prefetch: one h (8 slots) in flight; wave's slots = [wave*128, wave*128+128)
  const unsigned short* bp = Bc2 + (size_t)(wave * 128) * 512 + lane * 8;
  short8 bvr[8];
#pragma unroll
  for (int j = 0; j < 8; ++j) bvr[j] = *(const short8*)(bp + (size_t)j * 512);
  // gather out[src] rows -> packed fp16: 2 mf x 4 db x 4 dwords (32 VGPR)
  HU o8[2][4];
#pragma unroll
  for (int mf = 0; mf < 2; ++mf) {
    int e = e0 + mf * 32 + er;
    int s = (e < kE) ? ei[e] : 0;
    const float* base = outn + (size_t)s * 64 + hi5 * 8;
#pragma unroll
    for (int db = 0; db < 4; ++db) {
      floatx4 q0 = *(const floatx4*)(base + db * 16);
      floatx4 q1 = *(const floatx4*)(base + db * 16 + 4);
      o8[mf][db].u = (uint4){pkrtz(q0.x, q0.y), pkrtz(q0.z, q0.w),
                             pkrtz(q1.x, q1.y), pkrtz(q1.z, q1.w)};
    }
  }
  __syncthreads();   // hidS ready

  floatx16 acc[2][2];
#pragma unroll
  for (int mf = 0; mf < 2; ++mf)
#pragma unroll
    for (int nf = 0; nf < 2; ++nf)
#pragma unroll
      for (int i = 0; i < 16; ++i) acc[mf][nf][i] = 0.f;

  const int hl0 = wave * 16;
#pragma unroll 2
  for (int hh = 0; hh < 16; ++hh) {
    int hl = hl0 + hh;
    unsigned p0 = (unsigned)hidS[hl * 64 + er] * 0x10001u;       // fp16 splat
    unsigned p1 = (unsigned)hidS[hl * 64 + 32 + er] * 0x10001u;
    HU hv0, hv1;
    hv0.u = (uint4){p0, p0, p0, p0};
    hv1.u = (uint4){p1, p1, p1, p1};
    const unsigned short* bpn = bp + (size_t)((hh + 1) * 8) * 512;   // next h (max slot 1031)
#pragma unroll
    for (int db = 0; db < 4; ++db) {
      HU bv0, bv1;
      bv0.s = bvr[db * 2]; bv1.s = bvr[db * 2 + 1];
      bvr[db * 2]     = *(const short8*)(bpn + (size_t)(db * 2) * 512);
      bvr[db * 2 + 1] = *(const short8*)(bpn + (size_t)(db * 2 + 1) * 512);
      half8 a0 = o8[0][db].h * hv0.h;        // 4 v_pk_mul_f16, no converts
      half8 a1 = o8[1][db].h * hv1.h;
      acc[0][0] = __builtin_amdgcn_mfma_f32_32x32x16_f16(a0, bv0.h, acc[0][0], 0, 0, 0);
      acc[0][1] = __builtin_amdgcn_mfma_f32_32x32x16_f16(a0, bv1.h, acc[0][1], 0, 0, 0);
      acc[1][0] = __builtin_amdgcn_mfma_f32_32x32x16_f16(a1, bv0.h, acc[1][0], 0, 0, 0);
      acc[1][1] = __builtin_amdgcn_mfma_f32_32x32x16_f16(a1, bv1.h, acc[1][1], 0, 0, 0);
    }
  }
  if (wave == 7) {   // bias: msg += out @ reshape(be2,64,64) (A = out, fp16), once
#pragma unroll
    for (int db = 0; db < 4; ++db) {
      HU bv0, bv1;
      bv0.s = *(const short8*)(Bc2 + (size_t)(1024 + db * 2) * 512 + lane * 8);
      bv1.s = *(const short8*)(Bc2 + (size_t)(1024 + db * 2 + 1) * 512 + lane * 8);
      acc[0][0] = __builtin_amdgcn_mfma_f32_32x32x16_f16(o8[0][db].h, bv0.h, acc[0][0], 0, 0, 0);
      acc[0][1] = __builtin_amdgcn_mfma_f32_32x32x16_f16(o8[0][db].h, bv1.h, acc[0][1], 0, 0, 0);
      acc[1][0] = __builtin_amdgcn_mfma_f32_32x32x16_f16(o8[1][db].h, bv0.h, acc[1][0], 0, 0, 0);
      acc[1][1] = __builtin_amdgcn_mfma_f32_32x32x16_f16(o8[1][db].h, bv1.h, acc[1][1], 0, 0, 0);
    }
  }
  // chunked 8-way K-reduce: 2 chunks of 32 edges; conflict-free t*4 indexing
#pragma unroll
  for (int mf = 0; mf < 2; ++mf) {
#pragma unroll
    for (int nf = 0; nf < 2; ++nf)
#pragma unroll
      for (int reg = 0; reg < 16; ++reg) {
        int row = (reg & 3) + 8 * (reg >> 2) + 4 * hi5;   // 0..31 within chunk
        res[wave][row * 64 + nf * 32 + er] = acc[mf][nf][reg];
      }
    __syncthreads();
    {
      int idx = t * 4;                                   // 512 thr x float4 = 2048 elems
      float4 s4 = *(const float4*)&res[0][idx];
#pragma unroll
      for (int w = 1; w < 8; ++w) {
        float4 a4 = *(const float4*)&res[w][idx];
        s4.x += a4.x; s4.y += a4.y; s4.z += a4.z; s4.w += a4.w;
      }
      int e = e0 + mf * 32 + (idx >> 6);
      if (e < kE) {
        int pe = perm[e];                                // CSR-ordered destination row
        *(float4*)(msg + (size_t)pe * 64 + (idx & 63)) = s4;
      }
    }
    __syncthreads();
  }
}

// ==== NNConv-combine + GRU: contiguous CSR gather of single msg buffer ====
__global__ __launch_bounds__(256) void k_update(const float* __restrict__ msg,
    const int* __restrict__ ptr, const float* __restrict__ deg,
    const float* __restrict__ root, const float* __restrict__ convb,
    const float* __restrict__ Wi, const float* __restrict__ bi,
    const float* __restrict__ Wh, const float* __restrict__ bh,
    float* __restrict__ out) {
  __shared__ float sh_out[8][64];
  __shared__ float sh_m[8][64];
  int t = threadIdx.x, lane = t & 63, w = t >> 6;
  int nb = blockIdx.x * 8;
#pragma unroll
  for (int i = 0; i < 2; ++i) {
    int idx = t + i * 256;
    sh_out[idx >> 6][idx & 63] = out[(size_t)(nb + (idx >> 6)) * 64 + (idx & 63)];
  }
  __syncthreads();
  int n0 = w * 2;
  float acc[2];
#pragma unroll
  for (int i = 0; i < 2; ++i) {
    int n = nb + n0 + i;
    float dg = fmaxf(deg[n], 1.f);
    float s = 0.f;
    int p0 = ptr[n], p1 = ptr[n + 1];
    for (int k = p0; k < p1; ++k)            // contiguous rows, single buffer
      s += msg[(size_t)k * 64 + lane];
    acc[i] = s / dg + convb[lane];
  }
  for (int d = 0; d < 64; ++d) {
    float rv = root[d * 64 + lane];
#pragma unroll
    for (int i = 0; i < 2; ++i) acc[i] += sh_out[n0 + i][d] * rv;
  }
#pragma unroll
  for (int i = 0; i < 2; ++i) sh_m[n0 + i][lane] = fmaxf(acc[i], 0.f);
  __syncthreads();
  float ir[2] = {}, iz[2] = {}, ig[2] = {}, hr[2] = {}, hz[2] = {}, hg[2] = {};
  for (int d = 0; d < 64; ++d) {
    float wi0 = Wi[d * 192 + lane], wi1 = Wi[d * 192 + 64 + lane], wi2 = Wi[d * 192 + 128 + lane];
    float wh0 = Wh[d * 192 + lane], wh1 = Wh[d * 192 + 64 + lane], wh2 = Wh[d * 192 + 128 + lane];
#pragma unroll
    for (int i = 0; i < 2; ++i) {
      float mv = sh_m[n0 + i][d], hv = sh_out[n0 + i][d];
      ir[i] += mv * wi0; iz[i] += mv * wi1; ig[i] += mv * wi2;
      hr[i] += hv * wh0; hz[i] += hv * wh1; hg[i] += hv * wh2;
    }
  }
  float bi0 = bi[lane], bi1 = bi[64 + lane], bi2 = bi[128 + lane];
  float bh0 = bh[lane], bh1 = bh[64 + lane], bh2 = bh[128 + lane];
#pragma unroll
  for (int i = 0; i < 2; ++i) {
    float r = sigmf(ir[i] + bi0 + hr[i] + bh0);
    float z = sigmf(iz[i] + bi1 + hz[i] + bh1);
    float nn = tanh_(ig[i] + bi2 + r * (hg[i] + bh2));
    float h = sh_out[n0 + i][lane];
    out[(size_t)(nb + n0 + i) * 64 + lane] = (1.f - z) * nn + z * h;
  }
}

// ============ all 3 Set2Set steps + head1; graph's node rows staged in LDS ============
__global__ __launch_bounds__(256) void k_s2s3(const float* __restrict__ out,
    const int* __restrict__ start, const float* __restrict__ Wli,
    const float* __restrict__ bli, const float* __restrict__ Wlh,
    const float* __restrict__ blh, const float* __restrict__ Wr1,
    const float* __restrict__ br1, float* __restrict__ y1) {
  __shared__ float sno[kNCap * 65];     // node rows, stride 65 (bank-conflict-free)
  __shared__ float ebuf[1024];
  __shared__ float qs[128], hls[64], cls[64], gates[256];
  __shared__ float part[4][64];
  __shared__ float sred[8];
  int b = blockIdx.x, t = threadIdx.x, lane = t & 63, w = t >> 6;
  int s0 = start[b], s1 = start[b + 1];
  int cnt = s1 - s0; if (cnt > 1024) cnt = 1024;
  int cstg = cnt < kNCap ? cnt : kNCap;
  for (int i = t; i < cstg * 64; i += 256)
    sno[(i >> 6) * 65 + (i & 63)] = out[(size_t)(s0 + (i >> 6)) * 64 + (i & 63)];
  if (t < 128) qs[t] = 0.f;
  if (t < 64) { hls[t] = 0.f; cls[t] = 0.f; }
  __syncthreads();
  for (int it = 0; it < 3; ++it) {
    float g = bli[t] + blh[t];
    for (int j = 0; j < 128; ++j) g += qs[j] * Wli[j * 256 + t];
    for (int j = 0; j < 64; ++j) g += hls[j] * Wlh[j * 256 + t];
    gates[t] = g;
    __syncthreads();
    if (t < 64) {                      // gate order i, f, g, o
      float ig = sigmf(gates[t]), fg = sigmf(gates[64 + t]);
      float gg = tanh_(gates[128 + t]), og = sigmf(gates[192 + t]);
      float c = fg * cls[t] + ig * gg;
      float h = og * tanh_(c);
      cls[t] = c; hls[t] = h;
      qs[t] = h;                       // q part of q_star
    }
    __syncthreads();
    for (int n = t; n < cnt; n += 256) {        // e[n] = <out[n], q>
      float e = 0.f;
      if (n < kNCap) {
        const float* row = &sno[n * 65];
#pragma unroll 16
        for (int d = 0; d < 64; ++d) e += row[d] * hls[d];
      } else {
        const float* row = out + (size_t)(s0 + n) * 64;
        for (int d = 0; d < 64; ++d) e += row[d] * hls[d];
      }
      ebuf[n] = e;
    }
    __syncthreads();
    float mx = -3.4e38f;
    for (int idx = t; idx < cnt; idx += 256) mx = fmaxf(mx, ebuf[idx]);
#pragma unroll
    for (int m = 1; m < 64; m <<= 1) mx = fmaxf(mx, __shfl_xor(mx, m, 64));
    if (lane == 0) sred[w] = mx;
    __syncthreads();
    mx = fmaxf(fmaxf(sred[0], sred[1]), fmaxf(sred[2], sred[3]));
    float s = 0.f;
    for (int idx = t; idx < cnt; idx += 256) {
      float a = __expf(ebuf[idx] - mx);
      ebuf[idx] = a; s += a;
    }
#pragma unroll
    for (int m = 1; m < 64; m <<= 1) s += __shfl_xor(s, m, 64);
    if (lane == 0) sred[4 + w] = s;
    __syncthreads();
    s = sred[4] + sred[5] + sred[6] + sred[7];
    float rs = 1.f / fmaxf(s, 1e-12f);
    float pr = 0.f;
    for (int n = w; n < cnt; n += 4) {
      float a = ebuf[n];
      pr += a * ((n < kNCap) ? sno[n * 65 + lane] : out[(size_t)(s0 + n) * 64 + lane]);
    }
    part[w][lane] = pr;
    __syncthreads();
    if (t < 64)
      qs[64 + t] = (part[0][t] + part[1][t] + part[2][t] + part[3][t]) * rs;
    __syncthreads();
  }
  if (t < 64) {                        // head1: y1 = q_star @ Wr1 + br1
    float acc = br1[t];
    for (int j = 0; j < 128; ++j) acc += qs[j] * Wr1[j * 64 + t];
    y1[b * 64 + t] = acc;
  }
}

// ============ head2: BatchNorm (batch stats) + relu + Wr2 ============
__global__ __launch_bounds__(256) void k_head2(const float* __restrict__ y1,
    const float* __restrict__ gamma, const float* __restrict__ beta,
    const float* __restrict__ Wr2, const float* __restrict__ br2,
    float* __restrict__ outp) {
  __shared__ float mu[64], ri[64];
  int t = threadIdx.x;
  if (t < 64) {
    float s1 = 0.f, s2 = 0.f;
    for (int b = 0; b < kB; ++b) { float v = y1[b * 64 + t]; s1 += v; s2 += v * v; }
    float m = s1 / (float)kB;
    mu[t] = m; ri[t] = rsqrtf(s2 / (float)kB - m * m + 1e-5f);
  }
  __syncthreads();
  if (t < kB) {
    float acc = br2[0];
    for (int f = 0; f < 64; ++f) {
      float v = (y1[t * 64 + f] - mu[f]) * ri[f] * gamma[f] + beta[f];
      acc += fmaxf(v, 0.f) * Wr2[f];
    }
    outp[t] = acc;
  }
}

extern "C" void kernel_launch(void* const* d_in, const int* in_sizes, int n_in,
                              void* d_out, int out_size, void* d_ws, size_t ws_size,
                              hipStream_t stream) {
  const float* x     = (const float*)d_in[0];
  const int*   ei    = (const int*)d_in[1];
  const float* ea    = (const float*)d_in[2];
  const int*   batch = (const int*)d_in[3];
  const float* W0    = (const float*)d_in[4];
  const float* b0    = (const float*)d_in[5];
  const float* We1   = (const float*)d_in[6];
  const float* be1   = (const float*)d_in[7];
  const float* We2   = (const float*)d_in[8];
  const float* be2   = (const float*)d_in[9];
  const float* root  = (const float*)d_in[10];
  const float* convb = (const float*)d_in[11];
  const float* Wi    = (const float*)d_in[12];
  const float* bi    = (const float*)d_in[13];
  const float* Wh    = (const float*)d_in[14];
  const float* bh    = (const float*)d_in[15];
  const float* Wli   = (const float*)d_in[16];
  const float* bli   = (const float*)d_in[17];
  const float* Wlh   = (const float*)d_in[18];
  const float* blh   = (const float*)d_in[19];
  const float* Wr1   = (const float*)d_in[20];
  const float* br1   = (const float*)d_in[21];
  const float* gamma = (const float*)d_in[22];
  const float* beta  = (const float*)d_in[23];
  const float* Wr2   = (const float*)d_in[24];
  const float* br2   = (const float*)d_in[25];
  (void)in_sizes; (void)n_in; (void)out_size; (void)ws_size;

  char* ws = (char*)d_ws;
  size_t off = 0;
  auto take = [&](size_t bytes) {
    char* p = ws + off;
    off += (bytes + 255) & ~(size_t)255;
    return p;
  };
  // zero-region: deg + cnt (contiguous, one memset)
  float* deg  = (float*)take((size_t)kN * 4);
  int*   cnt  = (int*)take((size_t)kN * 4);
  size_t zeroBytes = off;
  int*   ptr   = (int*)take((size_t)(kN + 1) * 4);
  int*   perm  = (int*)take((size_t)kE * 4);
  int*   start = (int*)take(256 * 4);
  float* outn  = (float*)take((size_t)kN * kD * 4);
  float* msg   = (float*)take((size_t)kEPad * kD * 4);                     // 6.4 MB (single)
  unsigned short* hid7 = (unsigned short*)take((size_t)kGrp * 8192 * 2);   // 6.4 MB
  unsigned short* Bc2  = (unsigned short*)take((size_t)1032 * 512 * 2);    // 1.03 MB
  float* y1    = (float*)take((size_t)kB * 64 * 4);

  hipMemsetAsync(deg, 0, zeroBytes, stream);
  k_setup<<<kBlkSetup, 256, 0, stream>>>(x, W0, b0, ea, We1, be1, We2, be2, ei, batch,
                                         outn, hid7, Bc2, deg, start);
  k_csr<<<1, 256, 0, stream>>>(deg, ptr);
  k_scatter<<<(kE + 255) / 256, 256, 0, stream>>>(ei, ptr, cnt, perm);
  for (int s = 0; s < 3; ++s) {
    k_msgB<<<kGrp, 512, 0, stream>>>(ei, outn, hid7, Bc2, perm, msg);
    k_update<<<kN / 8, 256, 0, stream>>>(msg, ptr, deg, root, convb,
                                         Wi, bi, Wh, bh, outn);
  }
  k_s2s3<<<kB, 256, 0, stream>>>(outn, start, Wli, bli, Wlh, blh, Wr1, br1, y1);
  k_head2<<<1, 256, 0, stream>>>(y1, gamma, beta, Wr2, br2, (float*)d_out);
}

// Round 17
// 269.705 us; speedup vs baseline: 1.0553x; 1.0122x over previous
//
#include <hip/hip_runtime.h>
#include <hip/hip_bf16.h>

constexpr int kN = 10000;
constexpr int kE = 25000;
constexpr int kB = 128;
constexpr int kNF = 32;
constexpr int kEF = 8;
constexpr int kD = 64;
constexpr int kGrp = 392;          // 64-edge groups (25088 padded)
constexpr int kEPad = kGrp * 64;   // 25088
constexpr int kNCap = 320;         // s2s LDS node cap (global fallback beyond)

typedef __attribute__((ext_vector_type(8))) short short8;
typedef __attribute__((ext_vector_type(4))) float floatx4;
typedef __attribute__((ext_vector_type(16))) float floatx16;
typedef _Float16 half8 __attribute__((ext_vector_type(8)));

union HU { uint4 u; half8 h; short8 s; };

__device__ __forceinline__ unsigned short f2h(float f) {
  union { _Float16 h; unsigned short u; } cv;
  cv.h = (_Float16)f;
  return cv.u;
}
__device__ __forceinline__ unsigned pkrtz(float lo, float hi) {
  unsigned r;
  asm("v_cvt_pkrtz_f16_f32 %0, %1, %2" : "=v"(r) : "v"(lo), "v"(hi));
  return r;
}
__device__ __forceinline__ float sigmf(float x) { return 1.f / (1.f + __expf(-x)); }
__device__ __forceinline__ float tanh_(float x) { return 1.f - 2.f / (__expf(2.f * x) + 1.f); }

// ============ fused setup: dense0 | hidden fp16 | prep_b fp16 | deg | bounds ====
constexpr int kBlkDense = 2500;                 // kN*64/256
constexpr int kBlkHid   = 12544;                // 392*128*64/256
constexpr int kBlkPrep  = 258;                  // 1032 slots * 64 lanes / 256
constexpr int kBlkDeg   = 98;
constexpr int kB0H = kBlkDense;                 // 2500
constexpr int kB0P = kB0H + kBlkHid;            // 15044
constexpr int kB0G = kB0P + kBlkPrep;           // 15302
constexpr int kB0B = kB0G + kBlkDeg;            // 15400
constexpr int kBlkSetup = kB0B + 1;             // 15401

__global__ __launch_bounds__(256) void k_setup(
    const float* __restrict__ x, const float* __restrict__ W0, const float* __restrict__ b0,
    const float* __restrict__ ea, const float* __restrict__ We1, const float* __restrict__ be1,
    const float* __restrict__ We2, const float* __restrict__ be2,
    const int* __restrict__ ei, const int* __restrict__ batch,
    float* __restrict__ outn, unsigned short* __restrict__ hid7,
    unsigned short* __restrict__ Bc2, float* __restrict__ deg, int* __restrict__ start) {
  const int blk = blockIdx.x, t = threadIdx.x;
  if (blk < kB0H) {                   // ---- dense0: out = relu(x@W0+b0), [N,64]
    int gid = blk * 256 + t;
    int n = gid >> 6, f = gid & 63;
    float acc = b0[f];
    const float* xr = x + n * kNF;
#pragma unroll
    for (int j = 0; j < kNF; ++j) acc += xr[j] * W0[j * kD + f];
    outn[gid] = fmaxf(acc, 0.f);
  } else if (blk < kB0P) {            // ---- hidden: hid7[grp][h 128][e 64], fp16
    int gid = (blk - kB0H) * 256 + t;
    int e_loc = gid & 63, h = (gid >> 6) & 127, grp = gid >> 13;
    int e = grp * 64 + e_loc;
    float r = 0.f;
    if (e < kE) {
      float acc = be1[h];
      const float* er = ea + e * kEF;
#pragma unroll
      for (int j = 0; j < kEF; ++j) acc += er[j] * We1[j * 128 + h];
      r = fmaxf(acc, 0.f);
    }
    hid7[gid] = f2h(r);
  } else if (blk < kB0G) {            // ---- prep B: fragment-major Bc2 (32x32x16), fp16
    int lg = (blk - kB0P) * 256 + t;
    int lane = lg & 63, slot = lg >> 6;            // slot 0..1031
    int fcol, dbase;
    const float* srcmat;
    if (slot < 1024) {
      int nf_ = slot & 1, hdb = slot >> 1;         // slot = (h*4+db)*2+nf
      int db = hdb & 3, h = hdb >> 2;
      fcol = nf_ * 32 + (lane & 31);
      dbase = db * 16 + (lane >> 5) * 8;
      srcmat = We2 + (size_t)h * 4096;
    } else {
      int s = slot - 1024;
      int db = s >> 1, nf_ = s & 1;
      fcol = nf_ * 32 + (lane & 31);
      dbase = db * 16 + (lane >> 5) * 8;
      srcmat = be2;
    }
    unsigned short v[8];
#pragma unroll
    for (int j = 0; j < 8; ++j) v[j] = f2h(srcmat[(size_t)(dbase + j) * 64 + fcol]);
    *(short8*)(Bc2 + (size_t)slot * 512 + lane * 8) = *(short8*)v;
  } else if (blk < kB0B) {            // ---- degree
    int e = (blk - kB0G) * 256 + t;
    if (e < kE) atomicAdd(&deg[ei[kE + e]], 1.f);
  } else {                            // ---- per-graph bounds (batch sorted)
    if (t > kB) return;
    int lo = 0, hi = kN;
    while (lo < hi) { int mid = (lo + hi) >> 1; if (batch[mid] < t) lo = mid + 1; else hi = mid; }
    start[t] = lo;
  }
}

// ============ CSR build: scan (1 block) + scatter (saves perm[e]) ============
__global__ __launch_bounds__(256) void k_csr(const float* __restrict__ deg,
                                             int* __restrict__ ptr) {
  __shared__ int ps[256];
  int t = threadIdx.x;
  int base = t * 40;                       // 256*40 = 10240 >= kN
  int s = 0;
#pragma unroll 8
  for (int j = 0; j < 40; ++j) {
    int n = base + j;
    if (n < kN) s += (int)deg[n];
  }
  ps[t] = s;
  __syncthreads();
  for (int off = 1; off < 256; off <<= 1) {
    int v = (t >= off) ? ps[t - off] : 0;
    __syncthreads();
    ps[t] += v;
    __syncthreads();
  }
  int run = ps[t] - s;                     // exclusive prefix of this chunk
  for (int j = 0; j < 40; ++j) {
    int n = base + j;
    if (n < kN) { ptr[n] = run; run += (int)deg[n]; }
  }
  if (t == 255) ptr[kN] = ps[255];
}

__global__ __launch_bounds__(256) void k_scatter(const int* __restrict__ ei,
    const int* __restrict__ ptr, int* __restrict__ cnt, int* __restrict__ perm) {
  int e = blockIdx.x * 256 + threadIdx.x;
  if (e < kE) {
    int d = ei[kE + e];
    int pos = atomicAdd(&cnt[d], 1);
    perm[e] = ptr[d] + pos;                // edge e's row in csr-ordered msg buffer
  }
}

// ============ message GEMM (fp16 MFMA); stores rows in CSR order via perm ============
__global__ __launch_bounds__(256) void k_msgA(const int* __restrict__ ei,
    const float* __restrict__ outn, const unsigned short* __restrict__ hid7,
    const unsigned short* __restrict__ Bc2, const int* __restrict__ perm,
    float* __restrict__ msg0, float* __restrict__ msg1) {
  __shared__ __align__(16) unsigned short hidS[64 * 64];    // [h_loc][e_loc] fp16, 8 KB
  __shared__ __align__(16) float res[4][32 * 64];           // per-wave mf-chunk, 32 KB
  const int t = threadIdx.x, lane = t & 63, wave = t >> 6;
  const int er = lane & 31, hi5 = lane >> 5;
  const int grp = blockIdx.x, by = blockIdx.y, e0 = grp * 64;
  float* __restrict__ msgP = by ? msg1 : msg0;
  {   // stage hid K-half tile (8 KB linear)
    const char* hsrc = (const char*)(hid7 + (size_t)grp * 8192 + by * 4096);
#pragma unroll
    for (int i = 0; i < 2; ++i) {
      int off = (wave * 2 + i) * 1024 + lane * 16;
      __builtin_amdgcn_global_load_lds(
          (const __attribute__((address_space(1))) void*)(hsrc + off),
          (__attribute__((address_space(3))) void*)((char*)hidS + off), 16, 0, 0);
    }
  }
  // B prefetch: one h (8 slots: 4 db x 2 nf) in flight
  const int hg0 = by * 64 + wave * 16;                  // wave's first global h
  const unsigned short* bp = Bc2 + (size_t)(hg0 * 8) * 512 + lane * 8;
  short8 bvr[8];
#pragma unroll
  for (int j = 0; j < 8; ++j) bvr[j] = *(const short8*)(bp + (size_t)j * 512);
  // gather out[src] rows -> packed fp16: 2 mf x 4 db x 4 dwords (32 VGPR)
  HU o8[2][4];
#pragma unroll
  for (int mf = 0; mf < 2; ++mf) {
    int e = e0 + mf * 32 + er;
    int s = (e < kE) ? ei[e] : 0;
    const float* base = outn + (size_t)s * 64 + hi5 * 8;
#pragma unroll
    for (int db = 0; db < 4; ++db) {
      floatx4 q0 = *(const floatx4*)(base + db * 16);
      floatx4 q1 = *(const floatx4*)(base + db * 16 + 4);
      o8[mf][db].u = (uint4){pkrtz(q0.x, q0.y), pkrtz(q0.z, q0.w),
                             pkrtz(q1.x, q1.y), pkrtz(q1.z, q1.w)};
    }
  }
  __syncthreads();   // hidS ready

  floatx16 acc[2][2];
#pragma unroll
  for (int mf = 0; mf < 2; ++mf)
#pragma unroll
    for (int nf = 0; nf < 2; ++nf)
#pragma unroll
      for (int i = 0; i < 16; ++i) acc[mf][nf][i] = 0.f;

  const int hl0 = wave * 16;
#pragma unroll 2
  for (int hh = 0; hh < 16; ++hh) {
    int hl = hl0 + hh;
    unsigned p0 = (unsigned)hidS[hl * 64 + er] * 0x10001u;       // fp16 splat
    unsigned p1 = (unsigned)hidS[hl * 64 + 32 + er] * 0x10001u;
    HU hv0, hv1;
    hv0.u = (uint4){p0, p0, p0, p0};
    hv1.u = (uint4){p1, p1, p1, p1};
    const unsigned short* bpn = bp + (size_t)((hh + 1) * 8) * 512;   // next h (max slot 1031)
#pragma unroll
    for (int db = 0; db < 4; ++db) {
      HU bv0, bv1;
      bv0.s = bvr[db * 2]; bv1.s = bvr[db * 2 + 1];
      bvr[db * 2]     = *(const short8*)(bpn + (size_t)(db * 2) * 512);
      bvr[db * 2 + 1] = *(const short8*)(bpn + (size_t)(db * 2 + 1) * 512);
      half8 a0 = o8[0][db].h * hv0.h;        // 4 v_pk_mul_f16, no converts
      half8 a1 = o8[1][db].h * hv1.h;
      acc[0][0] = __builtin_amdgcn_mfma_f32_32x32x16_f16(a0, bv0.h, acc[0][0], 0, 0, 0);
      acc[0][1] = __builtin_amdgcn_mfma_f32_32x32x16_f16(a0, bv1.h, acc[0][1], 0, 0, 0);
      acc[1][0] = __builtin_amdgcn_mfma_f32_32x32x16_f16(a1, bv0.h, acc[1][0], 0, 0, 0);
      acc[1][1] = __builtin_amdgcn_mfma_f32_32x32x16_f16(a1, bv1.h, acc[1][1], 0, 0, 0);
    }
  }
  if (by == 1 && wave == 3) {   // bias: msg += out @ reshape(be2,64,64) (A = out, fp16)
#pragma unroll
    for (int db = 0; db < 4; ++db) {
      HU bv0, bv1;
      bv0.s = *(const short8*)(Bc2 + (size_t)(1024 + db * 2) * 512 + lane * 8);
      bv1.s = *(const short8*)(Bc2 + (size_t)(1024 + db * 2 + 1) * 512 + lane * 8);
      acc[0][0] = __builtin_amdgcn_mfma_f32_32x32x16_f16(o8[0][db].h, bv0.h, acc[0][0], 0, 0, 0);
      acc[0][1] = __builtin_amdgcn_mfma_f32_32x32x16_f16(o8[0][db].h, bv1.h, acc[0][1], 0, 0, 0);
      acc[1][0] = __builtin_amdgcn_mfma_f32_32x32x16_f16(o8[1][db].h, bv0.h, acc[1][0], 0, 0, 0);
      acc[1][1] = __builtin_amdgcn_mfma_f32_32x32x16_f16(o8[1][db].h, bv1.h, acc[1][1], 0, 0, 0);
    }
  }
  // chunked cross-wave reduce: 2 chunks of 32 edges; conflict-free t*4 indexing
#pragma unroll
  for (int mf = 0; mf < 2; ++mf) {
#pragma unroll
    for (int nf = 0; nf < 2; ++nf)
#pragma unroll
      for (int reg = 0; reg < 16; ++reg) {
        int row = (reg & 3) + 8 * (reg >> 2) + 4 * hi5;   // 0..31 within chunk
        res[wave][row * 64 + nf * 32 + er] = acc[mf][nf][reg];
      }
    __syncthreads();
#pragma unroll
    for (int q = 0; q < 2; ++q) {
      int idx = q * 1024 + t * 4;                        // float4 at elem 4t: conflict-free
      float4 s4 = *(const float4*)&res[0][idx];
#pragma unroll
      for (int w = 1; w < 4; ++w) {
        float4 a4 = *(const float4*)&res[w][idx];
        s4.x += a4.x; s4.y += a4.y; s4.z += a4.z; s4.w += a4.w;
      }
      int e = e0 + mf * 32 + (idx >> 6);
      if (e < kE) {
        int pe = perm[e];                                // CSR-ordered destination row
        *(float4*)(msgP + (size_t)pe * 64 + (idx & 63)) = s4;
      }
    }
    __syncthreads();
  }
}

// ==== NNConv-combine + GRU: contiguous CSR-range gather, 8 nodes/block ====
__global__ __launch_bounds__(256) void k_update(const float* __restrict__ msg0,
    const float* __restrict__ msg1, const int* __restrict__ ptr,
    const float* __restrict__ deg,
    const float* __restrict__ root, const float* __restrict__ convb,
    const float* __restrict__ Wi, const float* __restrict__ bi,
    const float* __restrict__ Wh, const float* __restrict__ bh,
    float* __restrict__ out) {
  __shared__ float sh_out[8][64];
  __shared__ float sh_m[8][64];
  int t = threadIdx.x, lane = t & 63, w = t >> 6;
  int nb = blockIdx.x * 8;
#pragma unroll
  for (int i = 0; i < 2; ++i) {
    int idx = t + i * 256;
    sh_out[idx >> 6][idx & 63] = out[(size_t)(nb + (idx >> 6)) * 64 + (idx & 63)];
  }
  __syncthreads();
  int n0 = w * 2;
  float acc[2];
#pragma unroll
  for (int i = 0; i < 2; ++i) {
    int n = nb + n0 + i;
    float dg = fmaxf(deg[n], 1.f);
    float s = 0.f;
    int p0 = ptr[n], p1 = ptr[n + 1];
    for (int k = p0; k < p1; ++k) {          // contiguous rows: address-independent loads
      size_t off2 = (size_t)k * 64 + lane;
      s += msg0[off2] + msg1[off2];
    }
    acc[i] = s / dg + convb[lane];
  }
  for (int d = 0; d < 64; ++d) {
    float rv = root[d * 64 + lane];
#pragma unroll
    for (int i = 0; i < 2; ++i) acc[i] += sh_out[n0 + i][d] * rv;
  }
#pragma unroll
  for (int i = 0; i < 2; ++i) sh_m[n0 + i][lane] = fmaxf(acc[i], 0.f);
  __syncthreads();
  float ir[2] = {}, iz[2] = {}, ig[2] = {}, hr[2] = {}, hz[2] = {}, hg[2] = {};
  for (int d = 0; d < 64; ++d) {
    float wi0 = Wi[d * 192 + lane], wi1 = Wi[d * 192 + 64 + lane], wi2 = Wi[d * 192 + 128 + lane];
    float wh0 = Wh[d * 192 + lane], wh1 = Wh[d * 192 + 64 + lane], wh2 = Wh[d * 192 + 128 + lane];
#pragma unroll
    for (int i = 0; i < 2; ++i) {
      float mv = sh_m[n0 + i][d], hv = sh_out[n0 + i][d];
      ir[i] += mv * wi0; iz[i] += mv * wi1; ig[i] += mv * wi2;
      hr[i] += hv * wh0; hz[i] += hv * wh1; hg[i] += hv * wh2;
    }
  }
  float bi0 = bi[lane], bi1 = bi[64 + lane], bi2 = bi[128 + lane];
  float bh0 = bh[lane], bh1 = bh[64 + lane], bh2 = bh[128 + lane];
#pragma unroll
  for (int i = 0; i < 2; ++i) {
    float r = sigmf(ir[i] + bi0 + hr[i] + bh0);
    float z = sigmf(iz[i] + bi1 + hz[i] + bh1);
    float nn = tanh_(ig[i] + bi2 + r * (hg[i] + bh2));
    float h = sh_out[n0 + i][lane];
    out[(size_t)(nb + n0 + i) * 64 + lane] = (1.f - z) * nn + z * h;
  }
}

// ============ all 3 Set2Set steps + head1; graph's node rows staged in LDS ============
__global__ __launch_bounds__(256) void k_s2s3(const float* __restrict__ out,
    const int* __restrict__ start, const float* __restrict__ Wli,
    const float* __restrict__ bli, const float* __restrict__ Wlh,
    const float* __restrict__ blh, const float* __restrict__ Wr1,
    const float* __restrict__ br1, float* __restrict__ y1) {
  __shared__ float sno[kNCap * 65];     // node rows, stride 65 (bank-conflict-free)
  __shared__ float ebuf[1024];
  __shared__ float qs[128], hls[64], cls[64], gates[256];
  __shared__ float part[4][64];
  __shared__ float sred[8];
  int b = blockIdx.x, t = threadIdx.x, lane = t & 63, w = t >> 6;
  int s0 = start[b], s1 = start[b + 1];
  int cnt = s1 - s0; if (cnt > 1024) cnt = 1024;
  int cstg = cnt < kNCap ? cnt : kNCap;
  for (int i = t; i < cstg * 64; i += 256)
    sno[(i >> 6) * 65 + (i & 63)] = out[(size_t)(s0 + (i >> 6)) * 64 + (i & 63)];
  if (t < 128) qs[t] = 0.f;
  if (t < 64) { hls[t] = 0.f; cls[t] = 0.f; }
  __syncthreads();
  for (int it = 0; it < 3; ++it) {
    float g = bli[t] + blh[t];
    for (int j = 0; j < 128; ++j) g += qs[j] * Wli[j * 256 + t];
    for (int j = 0; j < 64; ++j) g += hls[j] * Wlh[j * 256 + t];
    gates[t] = g;
    __syncthreads();
    if (t < 64) {                      // gate order i, f, g, o
      float ig = sigmf(gates[t]), fg = sigmf(gates[64 + t]);
      float gg = tanh_(gates[128 + t]), og = sigmf(gates[192 + t]);
      float c = fg * cls[t] + ig * gg;
      float h = og * tanh_(c);
      cls[t] = c; hls[t] = h;
      qs[t] = h;                       // q part of q_star
    }
    __syncthreads();
    for (int n = t; n < cnt; n += 256) {        // e[n] = <out[n], q>
      float e = 0.f;
      if (n < kNCap) {
        const float* row = &sno[n * 65];
#pragma unroll 16
        for (int d = 0; d < 64; ++d) e += row[d] * hls[d];
      } else {
        const float* row = out + (size_t)(s0 + n) * 64;
        for (int d = 0; d < 64; ++d) e += row[d] * hls[d];
      }
      ebuf[n] = e;
    }
    __syncthreads();
    float mx = -3.4e38f;
    for (int idx = t; idx < cnt; idx += 256) mx = fmaxf(mx, ebuf[idx]);
#pragma unroll
    for (int m = 1; m < 64; m <<= 1) mx = fmaxf(mx, __shfl_xor(mx, m, 64));
    if (lane == 0) sred[w] = mx;
    __syncthreads();
    mx = fmaxf(fmaxf(sred[0], sred[1]), fmaxf(sred[2], sred[3]));
    float s = 0.f;
    for (int idx = t; idx < cnt; idx += 256) {
      float a = __expf(ebuf[idx] - mx);
      ebuf[idx] = a; s += a;
    }
#pragma unroll
    for (int m = 1; m < 64; m <<= 1) s += __shfl_xor(s, m, 64);
    if (lane == 0) sred[4 + w] = s;
    __syncthreads();
    s = sred[4] + sred[5] + sred[6] + sred[7];
    float rs = 1.f / fmaxf(s, 1e-12f);
    float pr = 0.f;
    for (int n = w; n < cnt; n += 4) {
      float a = ebuf[n];
      pr += a * ((n < kNCap) ? sno[n * 65 + lane] : out[(size_t)(s0 + n) * 64 + lane]);
    }
    part[w][lane] = pr;
    __syncthreads();
    if (t < 64)
      qs[64 + t] = (part[0][t] + part[1][t] + part[2][t] + part[3][t]) * rs;
    __syncthreads();
  }
  if (t < 64) {                        // head1: y1 = q_star @ Wr1 + br1
    float acc = br1[t];
    for (int j = 0; j < 128; ++j) acc += qs[j] * Wr1[j * 64 + t];
    y1[b * 64 + t] = acc;
  }
}

// ============ head2: BatchNorm (batch stats) + relu + Wr2 ============
__global__ __launch_bounds__(256) void k_head2(const float* __restrict__ y1,
    const float* __restrict__ gamma, const float* __restrict__ beta,
    const float* __restrict__ Wr2, const float* __restrict__ br2,
    float* __restrict__ outp) {
  __shared__ float mu[64], ri[64];
  int t = threadIdx.x;
  if (t < 64) {
    float s1 = 0.f, s2 = 0.f;
    for (int b = 0; b < kB; ++b) { float v = y1[b * 64 + t]; s1 += v; s2 += v * v; }
    float m = s1 / (float)kB;
    mu[t] = m; ri[t] = rsqrtf(s2 / (float)kB - m * m + 1e-5f);
  }
  __syncthreads();
  if (t < kB) {
    float acc = br2[0];
    for (int f = 0; f < 64; ++f) {
      float v = (y1[t * 64 + f] - mu[f]) * ri[f] * gamma[f] + beta[f];
      acc += fmaxf(v, 0.f) * Wr2[f];
    }
    outp[t] = acc;
  }
}

extern "C" void kernel_launch(void* const* d_in, const int* in_sizes, int n_in,
                              void* d_out, int out_size, void* d_ws, size_t ws_size,
                              hipStream_t stream) {
  const float* x     = (const float*)d_in[0];
  const int*   ei    = (const int*)d_in[1];
  const float* ea    = (const float*)d_in[2];
  const int*   batch = (const int*)d_in[3];
  const float* W0    = (const float*)d_in[4];
  const float* b0    = (const float*)d_in[5];
  const float* We1   = (const float*)d_in[6];
  const float* be1   = (const float*)d_in[7];
  const float* We2   = (const float*)d_in[8];
  const float* be2   = (const float*)d_in[9];
  const float* root  = (const float*)d_in[10];
  const float* convb = (const float*)d_in[11];
  const float* Wi    = (const float*)d_in[12];
  const float* bi    = (const float*)d_in[13];
  const float* Wh    = (const float*)d_in[14];
  const float* bh    = (const float*)d_in[15];
  const float* Wli   = (const float*)d_in[16];
  const float* bli   = (const float*)d_in[17];
  const float* Wlh   = (const float*)d_in[18];
  const float* blh   = (const float*)d_in[19];
  const float* Wr1   = (const float*)d_in[20];
  const float* br1   = (const float*)d_in[21];
  const float* gamma = (const float*)d_in[22];
  const float* beta  = (const float*)d_in[23];
  const float* Wr2   = (const float*)d_in[24];
  const float* br2   = (const float*)d_in[25];
  (void)in_sizes; (void)n_in; (void)out_size; (void)ws_size;

  char* ws = (char*)d_ws;
  size_t off = 0;
  auto take = [&](size_t bytes) {
    char* p = ws + off;
    off += (bytes + 255) & ~(size_t)255;
    return p;
  };
  // zero-region: deg + cnt (contiguous, one memset)
  float* deg  = (float*)take((size_t)kN * 4);
  int*   cnt  = (int*)take((size_t)kN * 4);
  size_t zeroBytes = off;
  int*   ptr   = (int*)take((size_t)(kN + 1) * 4);
  int*   perm  = (int*)take((size_t)kE * 4);
  int*   start = (int*)take(256 * 4);
  float* outn  = (float*)take((size_t)kN * kD * 4);
  float* msg0  = (float*)take((size_t)kEPad * kD * 4);                     // 6.4 MB
  float* msg1  = (float*)take((size_t)kEPad * kD * 4);                     // 6.4 MB
  unsigned short* hid7 = (unsigned short*)take((size_t)kGrp * 8192 * 2);   // 6.4 MB
  unsigned short* Bc2  = (unsigned short*)take((size_t)1032 * 512 * 2);    // 1.03 MB
  float* y1    = (float*)take((size_t)kB * 64 * 4);

  hipMemsetAsync(deg, 0, zeroBytes, stream);
  k_setup<<<kBlkSetup, 256, 0, stream>>>(x, W0, b0, ea, We1, be1, We2, be2, ei, batch,
                                         outn, hid7, Bc2, deg, start);
  k_csr<<<1, 256, 0, stream>>>(deg, ptr);
  k_scatter<<<(kE + 255) / 256, 256, 0, stream>>>(ei, ptr, cnt, perm);
  dim3 gm(kGrp, 2);
  for (int s = 0; s < 3; ++s) {
    k_msgA<<<gm, 256, 0, stream>>>(ei, outn, hid7, Bc2, perm, msg0, msg1);
    k_update<<<kN / 8, 256, 0, stream>>>(msg0, msg1, ptr, deg, root, convb,
                                         Wi, bi, Wh, bh, outn);
  }
  k_s2s3<<<kB, 256, 0, stream>>>(outn, start, Wli, bli, Wlh, blh, Wr1, br1, y1);
  k_head2<<<1, 256, 0, stream>>>(y1, gamma, beta, Wr2, br2, (float*)d_out);
}